// Round 4
// baseline (1560.166 us; speedup 1.0000x reference)
//
#include <hip/hip_runtime.h>
#include <hip/hip_bf16.h>
#include <cstdint>
#include <cstddef>

#define BATCH   2048
#define DIM     1024   // D == H == 1024
#define NSTEPS  3      // RK4 steps; h = 1/NSTEPS
#define NBLK    256    // 1 block/CU (forced by 96 KB LDS), grid == CU count

typedef __attribute__((ext_vector_type(8))) short short8;
typedef __attribute__((ext_vector_type(4))) float f32x4;

static __device__ __forceinline__ unsigned short f2bf(float x) {
    union { float f; unsigned int u; } v; v.f = x;
    unsigned int r = v.u + 0x7FFFu + ((v.u >> 16) & 1u);  // round-to-nearest-even
    return (unsigned short)(r >> 16);
}

struct OdeArgs {
    const float* z0; const float* W1; const float* b1;
    const float* W2; const float* b2;
    float* zbuf;                       // d_out: fp32 state
    unsigned short* W1T; unsigned short* W2T;
    unsigned short* zin; unsigned short* hid;
    float* accb;
    unsigned int* bar;                 // grid-barrier counter (zeroed per call)
};

// ---------------------------------------------------------------------------
// ONE persistent kernel: prep (W->W^T bf16, z init) + 24 fused GEMM phases,
// separated by device-scope grid barriers (cooperative launch).
//
// Per phase: block tile 128x64, 4 waves, intra-block split-K (wave kh covers
// a 512-wide K half; rsub covers a 64-row half). Each wave = 64x64 output =
// 4x4 frags of mfma_f32_16x16x32_bf16. Double-buffered LDS, prefetch-then-
// compute, one workgroup barrier per K-step. K-halves combined via LDS.
//
// mode 0: hid = bf16(tanh(C+b))         mode 1: accb=k;  zin=bf16(z+(h/2)k)
// mode 2: accb+=2k; zin=bf16(z+(h/2)k)  mode 3: accb+=2k; zin=bf16(z+h k)
// mode 4: z+=(h/6)(accb+k); zin=bf16(z)
// ---------------------------------------------------------------------------
__global__ __launch_bounds__(256) void ode_all(OdeArgs a) {
    constexpr float hstep = 1.0f / NSTEPS;
    __shared__ short8 smem[2][3072];  // 96 KB

    const int tid  = threadIdx.x;
    const int wave = tid >> 6;
    const int lane = tid & 63;
    const int l15 = lane & 15, lhi = lane >> 4;
    const int rsub = wave & 1;   // row half within 128-row tile
    const int kh   = wave >> 1;  // K half
    const int bid  = blockIdx.x;
    const int bm = bid >> 4, bn = bid & 15;  // 16x16 tiles of 128x64

    unsigned int epoch = 0;
    auto gbar = [&]() {
        __threadfence();           // release: drain own stores + L2 writeback (cross-XCD)
        __syncthreads();
        ++epoch;
        if (tid == 0) {
            atomicAdd(a.bar, 1u);  // device-scope by default
            const unsigned target = (unsigned)NBLK * epoch;
            long spin = 0;
            while (__hip_atomic_load(a.bar, __ATOMIC_RELAXED, __HIP_MEMORY_SCOPE_AGENT) < target) {
                __builtin_amdgcn_s_sleep(2);
                if (++spin > (1L << 27)) break;  // safety: degrade to wrong-answer, never hang
            }
            __threadfence();       // acquire: invalidate L1/L2 before reading others' data
        }
        __syncthreads();
    };

    // ---------------- prep: W1^T, W2^T (bf16) + z/zin init ----------------
    {
        unsigned short (*tile)[65] = (unsigned short (*)[65])&smem[0][0];
        const int nb = (bid & 15) * 64, kb = (bid >> 4) * 64;
        const int cx = tid & 63, ry = tid >> 6;
        // W1
#pragma unroll
        for (int r = 0; r < 16; ++r) {
            int k = r * 4 + ry;
            tile[cx][k] = f2bf(a.W1[(size_t)(kb + k) * DIM + (nb + cx)]);
        }
        __syncthreads();
#pragma unroll
        for (int r = 0; r < 16; ++r) {
            int n = r * 4 + ry;
            a.W1T[(size_t)(nb + n) * DIM + (kb + cx)] = tile[n][cx];
        }
        __syncthreads();
        // W2
#pragma unroll
        for (int r = 0; r < 16; ++r) {
            int k = r * 4 + ry;
            tile[cx][k] = f2bf(a.W2[(size_t)(kb + k) * DIM + (nb + cx)]);
        }
        __syncthreads();
#pragma unroll
        for (int r = 0; r < 16; ++r) {
            int n = r * 4 + ry;
            a.W2T[(size_t)(nb + n) * DIM + (kb + cx)] = tile[n][cx];
        }
        // z init: 8 rows per block = 2048 float4, 8 per thread
        const float4* z4 = (const float4*)a.z0;
        float4* zb4 = (float4*)a.zbuf;
        ushort4* zi4 = (ushort4*)a.zin;
#pragma unroll
        for (int r = 0; r < 8; ++r) {
            const int i = bid * 2048 + r * 256 + tid;
            float4 v = z4[i];
            zb4[i] = v;
            ushort4 b;
            b.x = f2bf(v.x); b.y = f2bf(v.y); b.z = f2bf(v.z); b.w = f2bf(v.w);
            zi4[i] = b;
        }
    }
    gbar();

    // Per-lane staging offsets (elements) within the source matrices.
    // LDS slot s (16B, linear dest) holds global (row = s>>3, k16 = (s&7)^(row&7)).
    int offA[8], offB[4];
#pragma unroll
    for (int c = 0; c < 8; ++c) {
        const int g = c * 256 + tid;
        const int half = g >> 10, s = g & 1023;
        const int row = s >> 3, k16 = (s & 7) ^ (row & 7);
        offA[c] = (bm * 128 + row) * DIM + half * 512 + k16 * 8;
    }
#pragma unroll
    for (int c = 0; c < 4; ++c) {
        const int g = c * 256 + tid;
        const int half = g >> 9, s = g & 511;
        const int row = s >> 3, k16 = (s & 7) ^ (row & 7);
        offB[c] = (bn * 64 + row) * DIM + half * 512 + k16 * 8;
    }

    // ---------------- 24 GEMM phases ----------------
    for (int ph = 0; ph < NSTEPS * 8; ++ph) {
        const int sub = ph & 7;
        const bool g1 = (sub & 1) == 0;
        const int mode = g1 ? 0 : (sub >> 1) + 1;   // 0 | 1,2,3,4
        const unsigned short* A  = g1 ? a.zin : a.hid;
        const unsigned short* Bw = g1 ? a.W1T : a.W2T;
        const float* bias        = g1 ? a.b1  : a.b2;

        f32x4 acc[4][4] = {};

        auto stage = [&](int sbuf, int t) {
#pragma unroll
            for (int c = 0; c < 8; ++c)
                __builtin_amdgcn_global_load_lds(
                    (const __attribute__((address_space(1))) void*)(A + offA[c] + t * 64),
                    (__attribute__((address_space(3))) void*)&smem[sbuf][c * 256 + (wave << 6)],
                    16, 0, 0);
#pragma unroll
            for (int c = 0; c < 4; ++c)
                __builtin_amdgcn_global_load_lds(
                    (const __attribute__((address_space(1))) void*)(Bw + offB[c] + t * 64),
                    (__attribute__((address_space(3))) void*)&smem[sbuf][(8 + c) * 256 + (wave << 6)],
                    16, 0, 0);
        };

        stage(0, 0);
        __syncthreads();

        int buf = 0;
        for (int t = 0; t < 8; ++t) {
            if (t < 7) stage(buf ^ 1, t + 1);  // prefetch next K-step

            const char* sa = (const char*)&smem[buf][kh * 1024];
            const char* sb = (const char*)&smem[buf][2048 + kh * 512];
#pragma unroll
            for (int kk = 0; kk < 2; ++kk) {
                short8 af[4], bq[4];
#pragma unroll
                for (int m = 0; m < 4; ++m) {
                    const int row  = rsub * 64 + m * 16 + l15;
                    const int byte = row * 128 + ((kk * 64 + lhi * 16) ^ ((row & 7) << 4));
                    af[m] = *(const short8*)(sa + byte);
                }
#pragma unroll
                for (int n = 0; n < 4; ++n) {
                    const int row  = n * 16 + l15;
                    const int byte = row * 128 + ((kk * 64 + lhi * 16) ^ ((row & 7) << 4));
                    bq[n] = *(const short8*)(sb + byte);
                }
#pragma unroll
                for (int m = 0; m < 4; ++m)
#pragma unroll
                    for (int n = 0; n < 4; ++n)
                        acc[m][n] = __builtin_amdgcn_mfma_f32_16x16x32_bf16(af[m], bq[n], acc[m][n], 0, 0, 0);
            }
            __syncthreads();  // drains prefetch vmcnt + guards LDS buffer reuse
            buf ^= 1;
        }

        // combine K-halves via LDS, fused epilogue on kh==0 waves
        float* xch = (float*)&smem[0][0];
        if (kh == 1) {
            const int base = rsub * 4096;
#pragma unroll
            for (int m = 0; m < 4; ++m)
#pragma unroll
                for (int n = 0; n < 4; ++n)
#pragma unroll
                    for (int r = 0; r < 4; ++r)
                        xch[base + (m * 4 + n) * 256 + r * 64 + lane] = acc[m][n][r];
        }
        __syncthreads();
        if (kh == 0) {
            const int base = rsub * 4096;
#pragma unroll
            for (int m = 0; m < 4; ++m)
#pragma unroll
                for (int n = 0; n < 4; ++n) {
                    const int col = bn * 64 + n * 16 + l15;
                    const float bv = bias[col];
#pragma unroll
                    for (int r = 0; r < 4; ++r) {
                        const int row = bm * 128 + rsub * 64 + m * 16 + lhi * 4 + r;
                        const size_t idx = (size_t)row * DIM + col;
                        const float v = acc[m][n][r] + xch[base + (m * 4 + n) * 256 + r * 64 + lane] + bv;
                        if (mode == 0) {
                            a.hid[idx] = f2bf(tanhf(v));
                        } else if (mode == 1) {
                            a.accb[idx] = v;
                            a.zin[idx] = f2bf(a.zbuf[idx] + (0.5f * hstep) * v);
                        } else if (mode == 2) {
                            a.accb[idx] += 2.0f * v;
                            a.zin[idx] = f2bf(a.zbuf[idx] + (0.5f * hstep) * v);
                        } else if (mode == 3) {
                            a.accb[idx] += 2.0f * v;
                            a.zin[idx] = f2bf(a.zbuf[idx] + hstep * v);
                        } else {  // mode 4
                            const float zn = a.zbuf[idx] + (hstep / 6.0f) * (a.accb[idx] + v);
                            a.zbuf[idx] = zn;
                            a.zin[idx] = f2bf(zn);
                        }
                    }
                }
        }
        if (ph != NSTEPS * 8 - 1) gbar();
    }
}

// ---------------------------------------------------------------------------
extern "C" void kernel_launch(void* const* d_in, const int* in_sizes, int n_in,
                              void* d_out, int out_size, void* d_ws, size_t ws_size,
                              hipStream_t stream) {
    (void)in_sizes; (void)n_in; (void)out_size; (void)ws_size;
    char* ws = (char*)d_ws;

    OdeArgs args;
    args.z0   = (const float*)d_in[0];
    args.W1   = (const float*)d_in[1];
    args.b1   = (const float*)d_in[2];
    args.W2   = (const float*)d_in[3];
    args.b2   = (const float*)d_in[4];
    args.zbuf = (float*)d_out;
    args.W1T  = (unsigned short*)(ws);                 // 2 MB
    args.W2T  = (unsigned short*)(ws + (2u  << 20));   // 2 MB
    args.zin  = (unsigned short*)(ws + (4u  << 20));   // 4 MB
    args.hid  = (unsigned short*)(ws + (8u  << 20));   // 4 MB
    args.accb = (float*)         (ws + (12u << 20));   // 8 MB
    args.bar  = (unsigned int*)  (ws + (20u << 20));   // barrier counter

    // Barrier state must be zero at every call (harness poisons ws with 0xAA).
    hipMemsetAsync(args.bar, 0, 64, stream);

    void* kargs[] = { &args };
    hipError_t e = hipLaunchCooperativeKernel((const void*)ode_all,
                                              dim3(NBLK), dim3(256),
                                              kargs, 0, stream);
    if (e != hipSuccess) {
        // Fallback: plain launch. 96 KB LDS forces 1 block/CU and grid==CU
        // count, so co-residency still holds on a healthy 256-CU part.
        ode_all<<<dim3(NBLK), dim3(256), 0, stream>>>(args);
    }
}

// Round 5
// 334.202 us; speedup vs baseline: 4.6683x; 4.6683x over previous
//
#include <hip/hip_runtime.h>
#include <hip/hip_bf16.h>
#include <cstdint>
#include <cstddef>

#define BATCH   2048
#define DIM     1024   // D == H == 1024
#define NSTEPS  2      // RK4 steps; h = 1/NSTEPS

typedef __attribute__((ext_vector_type(8))) short short8;
typedef __attribute__((ext_vector_type(4))) float f32x4;

static __device__ __forceinline__ unsigned short f2bf(float x) {
    union { float f; unsigned int u; } v; v.f = x;
    unsigned int r = v.u + 0x7FFFu + ((v.u >> 16) & 1u);  // round-to-nearest-even
    return (unsigned short)(r >> 16);
}

// ---------------------------------------------------------------------------
// Transpose + convert: out[n*DIM + k] = bf16(in[k*DIM + n]).  (W -> W^T bf16)
// ---------------------------------------------------------------------------
__global__ __launch_bounds__(256) void transpose_conv(const float* __restrict__ in,
                                                      unsigned short* __restrict__ out) {
    __shared__ unsigned short tile[64][65];
    const int nb = blockIdx.x * 64, kb = blockIdx.y * 64;
    const int cx = threadIdx.x & 63, ry = threadIdx.x >> 6;
#pragma unroll
    for (int r = 0; r < 16; ++r) {
        int k = r * 4 + ry;
        tile[cx][k] = f2bf(in[(size_t)(kb + k) * DIM + (nb + cx)]);
    }
    __syncthreads();
#pragma unroll
    for (int r = 0; r < 16; ++r) {
        int n = r * 4 + ry;
        out[(size_t)(nb + n) * DIM + (kb + cx)] = tile[n][cx];
    }
}

// ---------------------------------------------------------------------------
// init: z (fp32 state, lives in d_out) = z0 ; zin (bf16 GEMM input) = bf16(z0)
// ---------------------------------------------------------------------------
__global__ __launch_bounds__(256) void init_state(const float* __restrict__ z0,
                                                  float* __restrict__ z,
                                                  unsigned short* __restrict__ zin) {
    const int i = blockIdx.x * 256 + threadIdx.x;
    float4 v = ((const float4*)z0)[i];
    ((float4*)z)[i] = v;
    ushort4 b;
    b.x = f2bf(v.x); b.y = f2bf(v.y); b.z = f2bf(v.z); b.w = f2bf(v.w);
    ((ushort4*)zin)[i] = b;
}

// ---------------------------------------------------------------------------
// GEMM: C[m][n] = sum_k A[m][k] * Bw[n][k]  (+ fused epilogue)
//
// Block tile 128x64, EIGHT waves (512 thr -> 2 waves/SIMD for latency hiding).
// Wave decomposition: wp = wave&1 (kk parity), rsub = (wave>>1)&1 (row half),
// kh = wave>>2 (K half). Each wave computes a PARTIAL 64x64 output:
// rows [rsub*64,+64), cols [0,64), K slice = kh-half, kk parity wp.
// => per wave per K-step: 8 ds_read_b128 + 16 MFMA (same 8 B/lane/MFMA reuse
// as R3; total LDS read traffic unchanged, now streamed by 8 waves).
// 4 partials per output combined via 96 KB LDS exchange in the epilogue.
// Double-buffered LDS (2 x 48 KB), prefetch-then-compute, 1 barrier/K-step.
// Grid = 16 x 16 = 256 blocks = 1 block/CU (96 KB LDS).
//
// MODE 0: hid = bf16(tanh(C+b))          MODE 1: accb=k;  zin=bf16(z+(h/2)k)
// MODE 2: accb+=2k; zin=bf16(z+(h/2)k)   MODE 3: accb+=2k; zin=bf16(z+h k)
// MODE 4: z+=(h/6)(accb+k); zin=bf16(z)
// ---------------------------------------------------------------------------
template<int MODE>
__global__ __launch_bounds__(512, 2) void gemm8w(const unsigned short* __restrict__ A,
                                                 const unsigned short* __restrict__ Bw,
                                                 const float* __restrict__ bias,
                                                 unsigned short* __restrict__ hidOut,
                                                 float* __restrict__ zbuf,
                                                 float* __restrict__ accb,
                                                 unsigned short* __restrict__ zinOut) {
    constexpr float hstep = 1.0f / NSTEPS;
    // smem[buf]: slots [0,2048) = A (half = s>>10: 128 rows x 64 k, swizzled)
    //            slots [2048,3072) = B (half = (s-2048)>>9: 64 rows x 64 k)
    __shared__ short8 smem[2][3072];  // 96 KB

    const int tid  = threadIdx.x;
    const int wave = tid >> 6;
    const int lane = tid & 63;
    const int l15 = lane & 15, lhi = lane >> 4;
    const int wp   = wave & 1;         // kk parity
    const int rsub = (wave >> 1) & 1;  // row half
    const int kh   = wave >> 2;        // K half
    const int bm = blockIdx.y, bn = blockIdx.x;

    f32x4 acc[4][4] = {};

    // Staging: 6 global_load_lds per thread cover 3072 slots.
    // LDS slot s (linear dest) holds global (row = s>>3, k16 = (s&7)^(row&7)).
    int offA[4], offB[2];
#pragma unroll
    for (int c = 0; c < 4; ++c) {
        const int g = c * 512 + tid;           // [0,2048)
        const int half = g >> 10, s = g & 1023;
        const int row = s >> 3, k16 = (s & 7) ^ (row & 7);
        offA[c] = (bm * 128 + row) * DIM + half * 512 + k16 * 8;
    }
#pragma unroll
    for (int c = 0; c < 2; ++c) {
        const int g = c * 512 + tid;           // [0,1024)
        const int half = g >> 9, s = g & 511;
        const int row = s >> 3, k16 = (s & 7) ^ (row & 7);
        offB[c] = (bn * 64 + row) * DIM + half * 512 + k16 * 8;
    }

    auto stage = [&](int sbuf, int t) {
#pragma unroll
        for (int c = 0; c < 4; ++c)
            __builtin_amdgcn_global_load_lds(
                (const __attribute__((address_space(1))) void*)(A + offA[c] + t * 64),
                (__attribute__((address_space(3))) void*)&smem[sbuf][c * 512 + (wave << 6)],
                16, 0, 0);
#pragma unroll
        for (int c = 0; c < 2; ++c)
            __builtin_amdgcn_global_load_lds(
                (const __attribute__((address_space(1))) void*)(Bw + offB[c] + t * 64),
                (__attribute__((address_space(3))) void*)&smem[sbuf][2048 + c * 512 + (wave << 6)],
                16, 0, 0);
    };

    stage(0, 0);
    __syncthreads();

    int buf = 0;
    for (int t = 0; t < 8; ++t) {
        if (t < 7) stage(buf ^ 1, t + 1);  // prefetch next K-step

        const char* sa = (const char*)&smem[buf][kh * 1024];
        const char* sb = (const char*)&smem[buf][2048 + kh * 512];
        // this wave's kk slice = wp
        short8 af[4], bq[4];
#pragma unroll
        for (int m = 0; m < 4; ++m) {
            const int row  = rsub * 64 + m * 16 + l15;
            const int byte = row * 128 + ((wp * 64 + lhi * 16) ^ ((row & 7) << 4));
            af[m] = *(const short8*)(sa + byte);
        }
#pragma unroll
        for (int n = 0; n < 4; ++n) {
            const int row  = n * 16 + l15;
            const int byte = row * 128 + ((wp * 64 + lhi * 16) ^ ((row & 7) << 4));
            bq[n] = *(const short8*)(sb + byte);
        }
#pragma unroll
        for (int m = 0; m < 4; ++m)
#pragma unroll
            for (int n = 0; n < 4; ++n)
                acc[m][n] = __builtin_amdgcn_mfma_f32_16x16x32_bf16(af[m], bq[n], acc[m][n], 0, 0, 0);

        __syncthreads();  // drains prefetch vmcnt + guards LDS buffer reuse
        buf ^= 1;
    }

    // ---- combine the 4 partials per 64x64 output via LDS ----
    // contributor id cidx = kh*2 + wp; cidx 0 is the owner (keeps acc in regs).
    float* xch = (float*)&smem[0][0];  // 6 regions x 16 KB = 96 KB
    const int cidx = kh * 2 + wp;
    if (cidx != 0) {
        const int base = (rsub * 3 + (cidx - 1)) * 4096;
#pragma unroll
        for (int m = 0; m < 4; ++m)
#pragma unroll
            for (int n = 0; n < 4; ++n)
#pragma unroll
                for (int r = 0; r < 4; ++r)
                    xch[base + (m * 4 + n) * 256 + r * 64 + lane] = acc[m][n][r];
    }
    __syncthreads();
    if (cidx == 0) {
        const int b0 = rsub * 3 * 4096;
#pragma unroll
        for (int m = 0; m < 4; ++m)
#pragma unroll
            for (int n = 0; n < 4; ++n) {
                const int col = bn * 64 + n * 16 + l15;
                const float bv = bias[col];
#pragma unroll
                for (int r = 0; r < 4; ++r) {
                    const int e = (m * 4 + n) * 256 + r * 64 + lane;
                    const int row = bm * 128 + rsub * 64 + m * 16 + lhi * 4 + r;
                    const size_t idx = (size_t)row * DIM + col;
                    const float v = acc[m][n][r] + xch[b0 + e] + xch[b0 + 4096 + e]
                                  + xch[b0 + 8192 + e] + bv;
                    if (MODE == 0) {
                        hidOut[idx] = f2bf(tanhf(v));
                    } else if (MODE == 1) {
                        accb[idx] = v;
                        zinOut[idx] = f2bf(zbuf[idx] + (0.5f * hstep) * v);
                    } else if (MODE == 2) {
                        accb[idx] += 2.0f * v;
                        zinOut[idx] = f2bf(zbuf[idx] + (0.5f * hstep) * v);
                    } else if (MODE == 3) {
                        accb[idx] += 2.0f * v;
                        zinOut[idx] = f2bf(zbuf[idx] + hstep * v);
                    } else {  // MODE 4
                        const float zn = zbuf[idx] + (hstep / 6.0f) * (accb[idx] + v);
                        zbuf[idx] = zn;
                        zinOut[idx] = f2bf(zn);
                    }
                }
            }
    }
}

// ---------------------------------------------------------------------------
extern "C" void kernel_launch(void* const* d_in, const int* in_sizes, int n_in,
                              void* d_out, int out_size, void* d_ws, size_t ws_size,
                              hipStream_t stream) {
    (void)in_sizes; (void)n_in; (void)out_size; (void)ws_size;
    const float* z0 = (const float*)d_in[0];
    const float* W1 = (const float*)d_in[1];
    const float* b1 = (const float*)d_in[2];
    const float* W2 = (const float*)d_in[3];
    const float* b2 = (const float*)d_in[4];
    float* zbuf = (float*)d_out;  // fp32 state lives in d_out

    char* ws = (char*)d_ws;
    unsigned short* W1T = (unsigned short*)(ws);                 // 2 MB
    unsigned short* W2T = (unsigned short*)(ws + (2u  << 20));   // 2 MB
    unsigned short* zin = (unsigned short*)(ws + (4u  << 20));   // 4 MB
    unsigned short* hid = (unsigned short*)(ws + (8u  << 20));   // 4 MB
    float*         accb = (float*)         (ws + (12u << 20));   // 8 MB

    dim3 tgrid(DIM / 64, DIM / 64);
    transpose_conv<<<tgrid, 256, 0, stream>>>(W1, W1T);
    transpose_conv<<<tgrid, 256, 0, stream>>>(W2, W2T);
    init_state<<<(BATCH * DIM / 4) / 256, 256, 0, stream>>>(z0, zbuf, zin);

    dim3 ggrid(DIM / 64, BATCH / 128);  // 16 x 16 = 256 blocks
    for (int s = 0; s < NSTEPS; ++s) {
        gemm8w<0><<<ggrid, 512, 0, stream>>>(zin, W1T, b1, hid, nullptr, nullptr, nullptr);
        gemm8w<1><<<ggrid, 512, 0, stream>>>(hid, W2T, b2, nullptr, zbuf, accb, zin);
        gemm8w<0><<<ggrid, 512, 0, stream>>>(zin, W1T, b1, hid, nullptr, nullptr, nullptr);
        gemm8w<2><<<ggrid, 512, 0, stream>>>(hid, W2T, b2, nullptr, zbuf, accb, zin);
        gemm8w<0><<<ggrid, 512, 0, stream>>>(zin, W1T, b1, hid, nullptr, nullptr, nullptr);
        gemm8w<3><<<ggrid, 512, 0, stream>>>(hid, W2T, b2, nullptr, zbuf, accb, zin);
        gemm8w<0><<<ggrid, 512, 0, stream>>>(zin, W1T, b1, hid, nullptr, nullptr, nullptr);
        gemm8w<4><<<ggrid, 512, 0, stream>>>(hid, W2T, b2, nullptr, zbuf, accb, zin);
    }
}

// Round 6
// 299.634 us; speedup vs baseline: 5.2069x; 1.1154x over previous
//
#include <hip/hip_runtime.h>
#include <hip/hip_bf16.h>
#include <cstdint>
#include <cstddef>

#define BATCH   2048
#define DIM     1024   // D == H == 1024
#define NSTEPS  2      // RK4 steps; h = 1/NSTEPS

typedef __attribute__((ext_vector_type(8))) short short8;
typedef __attribute__((ext_vector_type(4))) float f32x4;

static __device__ __forceinline__ unsigned short f2bf(float x) {
    union { float f; unsigned int u; } v; v.f = x;
    unsigned int r = v.u + 0x7FFFu + ((v.u >> 16) & 1u);  // round-to-nearest-even
    return (unsigned short)(r >> 16);
}

// ---------------------------------------------------------------------------
// Fused prep (ONE dispatch): z/zin init (all 2048 blocks) + W1/W2 transpose
// to bf16 [N][K] (blocks 0..511, one 64x64 tile each).
// ---------------------------------------------------------------------------
__global__ __launch_bounds__(256) void prep_all(const float* __restrict__ W1,
                                                const float* __restrict__ W2,
                                                const float* __restrict__ z0,
                                                float* __restrict__ z,
                                                unsigned short* __restrict__ W1T,
                                                unsigned short* __restrict__ W2T,
                                                unsigned short* __restrict__ zin) {
    __shared__ unsigned short tile[64][65];
    const int b = blockIdx.x;

    // init: one float4 per thread (2048 blocks x 256 thr x 4 = 2M elems)
    {
        const int i = b * 256 + threadIdx.x;
        float4 v = ((const float4*)z0)[i];
        ((float4*)z)[i] = v;
        ushort4 q;
        q.x = f2bf(v.x); q.y = f2bf(v.y); q.z = f2bf(v.z); q.w = f2bf(v.w);
        ((ushort4*)zin)[i] = q;
    }

    if (b < 512) {  // transpose one 64x64 tile of W1 (b<256) or W2
        const float* in = (b < 256) ? W1 : W2;
        unsigned short* out = (b < 256) ? W1T : W2T;
        const int tb = b & 255;
        const int nb = (tb & 15) * 64, kb = (tb >> 4) * 64;
        const int cx = threadIdx.x & 63, ry = threadIdx.x >> 6;
#pragma unroll
        for (int r = 0; r < 16; ++r) {
            int k = r * 4 + ry;
            tile[cx][k] = f2bf(in[(size_t)(kb + k) * DIM + (nb + cx)]);
        }
        __syncthreads();
#pragma unroll
        for (int r = 0; r < 16; ++r) {
            int n = r * 4 + ry;
            out[(size_t)(nb + n) * DIM + (kb + cx)] = tile[n][cx];
        }
    }
}

// ---------------------------------------------------------------------------
// GEMM: C[m][n] = sum_k A[m][k] * Bw[n][k]  (+ fused epilogue)
//
// Block tile 128x64, 8 waves (512 thr, 2 waves/SIMD). Wave = (wp = kk parity,
// rsub = row half, kh = K half); each wave a partial 64x64 output (4x4 frags
// of mfma_f32_16x16x32_bf16). 4 partials combined via LDS in the epilogue.
//
// TRIPLE-buffered LDS (3 x 48 KB), counted-vmcnt pipeline (T3/T4, m218):
//   prologue: stage(0), stage(1)                      (12 loads in flight)
//   iter t:   s_waitcnt vmcnt(6|0)  -> stage(t) landed (issued 2 iters ago)
//             s_barrier             -> all waves' stage(t) visible; buf(t+2)%3 free
//             stage(t+2)            -> loads stay in flight ACROSS the barrier
//             compute(t)
// No vmcnt(0) drain in the main loop.
//
// MODE 0: hid = bf16(tanh(C+b))          MODE 1: accb=k;  zin=bf16(z+(h/2)k)
// MODE 2: accb+=2k; zin=bf16(z+(h/2)k)   MODE 3: accb+=2k; zin=bf16(z+h k)
// MODE 4: z+=(h/6)(accb+k); zin=bf16(z)
// ---------------------------------------------------------------------------
template<int MODE>
__global__ __launch_bounds__(512, 2) void gemm8w(const unsigned short* __restrict__ A,
                                                 const unsigned short* __restrict__ Bw,
                                                 const float* __restrict__ bias,
                                                 unsigned short* __restrict__ hidOut,
                                                 float* __restrict__ zbuf,
                                                 float* __restrict__ accb,
                                                 unsigned short* __restrict__ zinOut) {
    constexpr float hstep = 1.0f / NSTEPS;
    // smem[buf]: slots [0,2048) = A (128 rows x 64 k, swizzled), [2048,3072) = B.
    __shared__ short8 smem[3][3072];  // 144 KB

    const int tid  = threadIdx.x;
    const int wave = tid >> 6;
    const int lane = tid & 63;
    const int l15 = lane & 15, lhi = lane >> 4;
    const int wp   = wave & 1;         // kk parity
    const int rsub = (wave >> 1) & 1;  // row half
    const int kh   = wave >> 2;        // K half
    const int bm = blockIdx.y, bn = blockIdx.x;

    f32x4 acc[4][4] = {};

    // Staging: 6 global_load_lds per thread (4 A + 2 B) cover 3072 slots.
    // LDS slot s (linear dest) holds global (row = s>>3, k16 = (s&7)^(row&7)).
    int offA[4], offB[2];
#pragma unroll
    for (int c = 0; c < 4; ++c) {
        const int g = c * 512 + tid;           // [0,2048)
        const int half = g >> 10, s = g & 1023;
        const int row = s >> 3, k16 = (s & 7) ^ (row & 7);
        offA[c] = (bm * 128 + row) * DIM + half * 512 + k16 * 8;
    }
#pragma unroll
    for (int c = 0; c < 2; ++c) {
        const int g = c * 512 + tid;           // [0,1024)
        const int half = g >> 9, s = g & 511;
        const int row = s >> 3, k16 = (s & 7) ^ (row & 7);
        offB[c] = (bn * 64 + row) * DIM + half * 512 + k16 * 8;
    }

    auto stage = [&](int sbuf, int t) {
#pragma unroll
        for (int c = 0; c < 4; ++c)
            __builtin_amdgcn_global_load_lds(
                (const __attribute__((address_space(1))) void*)(A + offA[c] + t * 64),
                (__attribute__((address_space(3))) void*)&smem[sbuf][c * 512 + (wave << 6)],
                16, 0, 0);
#pragma unroll
        for (int c = 0; c < 2; ++c)
            __builtin_amdgcn_global_load_lds(
                (const __attribute__((address_space(1))) void*)(Bw + offB[c] + t * 64),
                (__attribute__((address_space(3))) void*)&smem[sbuf][2048 + c * 512 + (wave << 6)],
                16, 0, 0);
    };

    stage(0, 0);
    stage(1, 1);  // 12 loads in flight

    for (int t = 0; t < 8; ++t) {
        // wait for stage(t)'s 6 loads; keep the newest 6 (stage t+1) in flight
        if (t < 7) asm volatile("s_waitcnt vmcnt(6)" ::: "memory");
        else       asm volatile("s_waitcnt vmcnt(0)" ::: "memory");
        __builtin_amdgcn_s_barrier();          // raw: no vmcnt(0) drain
        __builtin_amdgcn_sched_barrier(0);     // don't hoist stage above barrier

        if (t + 2 < 8) stage((t + 2) % 3, t + 2);

        const char* sa = (const char*)&smem[t % 3][kh * 1024];
        const char* sb = (const char*)&smem[t % 3][2048 + kh * 512];
        short8 af[4], bq[4];
#pragma unroll
        for (int m = 0; m < 4; ++m) {
            const int row  = rsub * 64 + m * 16 + l15;
            const int byte = row * 128 + ((wp * 64 + lhi * 16) ^ ((row & 7) << 4));
            af[m] = *(const short8*)(sa + byte);
        }
#pragma unroll
        for (int n = 0; n < 4; ++n) {
            const int row  = n * 16 + l15;
            const int byte = row * 128 + ((wp * 64 + lhi * 16) ^ ((row & 7) << 4));
            bq[n] = *(const short8*)(sb + byte);
        }
#pragma unroll
        for (int m = 0; m < 4; ++m)
#pragma unroll
            for (int n = 0; n < 4; ++n)
                acc[m][n] = __builtin_amdgcn_mfma_f32_16x16x32_bf16(af[m], bq[n], acc[m][n], 0, 0, 0);
    }

    __syncthreads();  // all waves done computing before xch overwrites bufs 0/1

    // ---- combine the 4 partials per 64x64 output via LDS ----
    // contributor cidx = kh*2 + wp; cidx 0 keeps its acc in regs.
    float* xch = (float*)&smem[0][0];  // 6 regions x 16 KB = 96 KB (bufs 0+1)
    const int cidx = kh * 2 + wp;
    if (cidx != 0) {
        const int base = (rsub * 3 + (cidx - 1)) * 4096;
#pragma unroll
        for (int m = 0; m < 4; ++m)
#pragma unroll
            for (int n = 0; n < 4; ++n)
#pragma unroll
                for (int r = 0; r < 4; ++r)
                    xch[base + (m * 4 + n) * 256 + r * 64 + lane] = acc[m][n][r];
    }
    __syncthreads();
    if (cidx == 0) {
        const int b0 = rsub * 3 * 4096;
#pragma unroll
        for (int m = 0; m < 4; ++m)
#pragma unroll
            for (int n = 0; n < 4; ++n) {
                const int col = bn * 64 + n * 16 + l15;
                const float bv = bias[col];
#pragma unroll
                for (int r = 0; r < 4; ++r) {
                    const int e = (m * 4 + n) * 256 + r * 64 + lane;
                    const int row = bm * 128 + rsub * 64 + m * 16 + lhi * 4 + r;
                    const size_t idx = (size_t)row * DIM + col;
                    const float v = acc[m][n][r] + xch[b0 + e] + xch[b0 + 4096 + e]
                                  + xch[b0 + 8192 + e] + bv;
                    if (MODE == 0) {
                        hidOut[idx] = f2bf(tanhf(v));
                    } else if (MODE == 1) {
                        accb[idx] = v;
                        zinOut[idx] = f2bf(zbuf[idx] + (0.5f * hstep) * v);
                    } else if (MODE == 2) {
                        accb[idx] += 2.0f * v;
                        zinOut[idx] = f2bf(zbuf[idx] + (0.5f * hstep) * v);
                    } else if (MODE == 3) {
                        accb[idx] += 2.0f * v;
                        zinOut[idx] = f2bf(zbuf[idx] + hstep * v);
                    } else {  // MODE 4
                        const float zn = zbuf[idx] + (hstep / 6.0f) * (accb[idx] + v);
                        zbuf[idx] = zn;
                        zinOut[idx] = f2bf(zn);
                    }
                }
            }
    }
}

// ---------------------------------------------------------------------------
extern "C" void kernel_launch(void* const* d_in, const int* in_sizes, int n_in,
                              void* d_out, int out_size, void* d_ws, size_t ws_size,
                              hipStream_t stream) {
    (void)in_sizes; (void)n_in; (void)out_size; (void)ws_size;
    const float* z0 = (const float*)d_in[0];
    const float* W1 = (const float*)d_in[1];
    const float* b1 = (const float*)d_in[2];
    const float* W2 = (const float*)d_in[3];
    const float* b2 = (const float*)d_in[4];
    float* zbuf = (float*)d_out;  // fp32 state lives in d_out

    char* ws = (char*)d_ws;
    unsigned short* W1T = (unsigned short*)(ws);                 // 2 MB
    unsigned short* W2T = (unsigned short*)(ws + (2u  << 20));   // 2 MB
    unsigned short* zin = (unsigned short*)(ws + (4u  << 20));   // 4 MB
    unsigned short* hid = (unsigned short*)(ws + (8u  << 20));   // 4 MB
    float*         accb = (float*)         (ws + (12u << 20));   // 8 MB

    prep_all<<<(BATCH * DIM / 4) / 256, 256, 0, stream>>>(W1, W2, z0, zbuf, W1T, W2T, zin);

    dim3 ggrid(DIM / 64, BATCH / 128);  // 16 x 16 = 256 blocks
    for (int s = 0; s < NSTEPS; ++s) {
        gemm8w<0><<<ggrid, 512, 0, stream>>>(zin, W1T, b1, hid, nullptr, nullptr, nullptr);
        gemm8w<1><<<ggrid, 512, 0, stream>>>(hid, W2T, b2, nullptr, zbuf, accb, zin);
        gemm8w<0><<<ggrid, 512, 0, stream>>>(zin, W1T, b1, hid, nullptr, nullptr, nullptr);
        gemm8w<2><<<ggrid, 512, 0, stream>>>(hid, W2T, b2, nullptr, zbuf, accb, zin);
        gemm8w<0><<<ggrid, 512, 0, stream>>>(zin, W1T, b1, hid, nullptr, nullptr, nullptr);
        gemm8w<3><<<ggrid, 512, 0, stream>>>(hid, W2T, b2, nullptr, zbuf, accb, zin);
        gemm8w<0><<<ggrid, 512, 0, stream>>>(zin, W1T, b1, hid, nullptr, nullptr, nullptr);
        gemm8w<4><<<ggrid, 512, 0, stream>>>(hid, W2T, b2, nullptr, zbuf, accb, zin);
    }
}

// Round 7
// 213.944 us; speedup vs baseline: 7.2924x; 1.4005x over previous
//
#include <hip/hip_runtime.h>
#include <hip/hip_bf16.h>
#include <cstdint>
#include <cstddef>

#define BATCH   2048
#define DIM     1024   // D == H == 1024
#define NSTEPS  2      // RK4 steps; h = 1/NSTEPS

typedef __attribute__((ext_vector_type(8))) short short8;
typedef __attribute__((ext_vector_type(4))) float f32x4;
typedef _Float16 half8 __attribute__((ext_vector_type(8)));

static __device__ __forceinline__ unsigned short f2h(float x) {
    _Float16 h = (_Float16)x;                    // v_cvt_f16_f32 (RTN)
    return __builtin_bit_cast(unsigned short, h);
}

// ---------------------------------------------------------------------------
// Fused prep (ONE dispatch): z/zin init (all 2048 blocks) + W1/W2 transpose
// to f16 [N][K] (blocks 0..511, one 64x64 tile each).
// ---------------------------------------------------------------------------
__global__ __launch_bounds__(256) void prep_all(const float* __restrict__ W1,
                                                const float* __restrict__ W2,
                                                const float* __restrict__ z0,
                                                float* __restrict__ z,
                                                unsigned short* __restrict__ W1T,
                                                unsigned short* __restrict__ W2T,
                                                unsigned short* __restrict__ zin) {
    __shared__ unsigned short tile[64][65];
    const int b = blockIdx.x;

    {   // init: one float4 per thread
        const int i = b * 256 + threadIdx.x;
        float4 v = ((const float4*)z0)[i];
        ((float4*)z)[i] = v;
        ushort4 q;
        q.x = f2h(v.x); q.y = f2h(v.y); q.z = f2h(v.z); q.w = f2h(v.w);
        ((ushort4*)zin)[i] = q;
    }

    if (b < 512) {  // transpose one 64x64 tile of W1 (b<256) or W2
        const float* in = (b < 256) ? W1 : W2;
        unsigned short* out = (b < 256) ? W1T : W2T;
        const int tb = b & 255;
        const int nb = (tb & 15) * 64, kb = (tb >> 4) * 64;
        const int cx = threadIdx.x & 63, ry = threadIdx.x >> 6;
#pragma unroll
        for (int r = 0; r < 16; ++r) {
            int k = r * 4 + ry;
            tile[cx][k] = f2h(in[(size_t)(kb + k) * DIM + (nb + cx)]);
        }
        __syncthreads();
#pragma unroll
        for (int r = 0; r < 16; ++r) {
            int n = r * 4 + ry;
            out[(size_t)(nb + n) * DIM + (kb + cx)] = tile[n][cx];
        }
    }
}

// ---------------------------------------------------------------------------
// GEMM: C[m][n] = sum_k A[m][k] * Bw[n][k]  (+ fused epilogue), f16 inputs.
//
// Main loop: block tile 128x64, 8 waves (2/SIMD). Wave = (wp = kk parity,
// rsub = row half, kh = K half); partial 64x64 per wave (4x4 frags of
// mfma_f32_16x16x32_f16). Triple-buffered LDS + counted-vmcnt pipeline (T3/T4).
//
// Epilogue: ALL 8 waves write partials to a 135 KB LDS exchange
// (region stride 4224 f32; inner stride 264 breaks bank alignment), then all
// 512 threads each own one row x 16 contiguous cols: 16x ds_read_b128 +
// fully vectorized f32x4 / short8 global I/O.
//
// MODE 0: hid = f16(tanh(C+b))           MODE 1: accb=k;  zin=f16(z+(h/2)k)
// MODE 2: accb+=2k; zin=f16(z+(h/2)k)    MODE 3: accb+=2k; zin=f16(z+h k)
// MODE 4: z+=(h/6)(accb+k); zin=f16(z)
// ---------------------------------------------------------------------------
template<int MODE>
__global__ __launch_bounds__(512) void gemm8w(const unsigned short* __restrict__ A,
                                              const unsigned short* __restrict__ Bw,
                                              const float* __restrict__ bias,
                                              unsigned short* __restrict__ hidOut,
                                              float* __restrict__ zbuf,
                                              float* __restrict__ accb,
                                              unsigned short* __restrict__ zinOut) {
    constexpr float hstep = 1.0f / NSTEPS;
    __shared__ char smem_raw[147456];            // 144 KB (staging ∪ exchange)
    short8* stg = (short8*)smem_raw;             // 3 bufs x 3072 slots
    float*  xch = (float*)smem_raw;              // 8 regions x 4224 f32 = 135 KB

    const int tid  = threadIdx.x;
    const int wave = tid >> 6;
    const int lane = tid & 63;
    const int l15 = lane & 15, lhi = lane >> 4;
    const int wp   = wave & 1;         // kk parity
    const int rsub = (wave >> 1) & 1;  // row half
    const int kh   = wave >> 2;        // K half
    const int bm = blockIdx.y, bn = blockIdx.x;

    f32x4 acc[4][4] = {};

    // Staging: 6 global_load_lds per thread (4 A + 2 B) cover 3072 slots.
    // LDS slot s (linear dest) holds global (row = s>>3, k16 = (s&7)^(row&7)).
    int offA[4], offB[2];
#pragma unroll
    for (int c = 0; c < 4; ++c) {
        const int g = c * 512 + tid;           // [0,2048)
        const int half = g >> 10, s = g & 1023;
        const int row = s >> 3, k16 = (s & 7) ^ (row & 7);
        offA[c] = (bm * 128 + row) * DIM + half * 512 + k16 * 8;
    }
#pragma unroll
    for (int c = 0; c < 2; ++c) {
        const int g = c * 512 + tid;           // [0,1024)
        const int half = g >> 9, s = g & 511;
        const int row = s >> 3, k16 = (s & 7) ^ (row & 7);
        offB[c] = (bn * 64 + row) * DIM + half * 512 + k16 * 8;
    }

    auto stage = [&](int sbuf, int t) {
#pragma unroll
        for (int c = 0; c < 4; ++c)
            __builtin_amdgcn_global_load_lds(
                (const __attribute__((address_space(1))) void*)(A + offA[c] + t * 64),
                (__attribute__((address_space(3))) void*)&stg[sbuf * 3072 + c * 512 + (wave << 6)],
                16, 0, 0);
#pragma unroll
        for (int c = 0; c < 2; ++c)
            __builtin_amdgcn_global_load_lds(
                (const __attribute__((address_space(1))) void*)(Bw + offB[c] + t * 64),
                (__attribute__((address_space(3))) void*)&stg[sbuf * 3072 + 2048 + c * 512 + (wave << 6)],
                16, 0, 0);
    };

    stage(0, 0);
    stage(1, 1);  // 12 loads in flight

    for (int t = 0; t < 8; ++t) {
        if (t < 7) asm volatile("s_waitcnt vmcnt(6)" ::: "memory");
        else       asm volatile("s_waitcnt vmcnt(0)" ::: "memory");
        __builtin_amdgcn_s_barrier();          // raw: no vmcnt(0) drain
        __builtin_amdgcn_sched_barrier(0);     // don't hoist stage above barrier

        if (t + 2 < 8) stage((t + 2) % 3, t + 2);

        const char* sa = (const char*)&stg[(t % 3) * 3072 + kh * 1024];
        const char* sb = (const char*)&stg[(t % 3) * 3072 + 2048 + kh * 512];
        half8 af[4], bq[4];
#pragma unroll
        for (int m = 0; m < 4; ++m) {
            const int row  = rsub * 64 + m * 16 + l15;
            const int byte = row * 128 + ((wp * 64 + lhi * 16) ^ ((row & 7) << 4));
            af[m] = *(const half8*)(sa + byte);
        }
#pragma unroll
        for (int n = 0; n < 4; ++n) {
            const int row  = n * 16 + l15;
            const int byte = row * 128 + ((wp * 64 + lhi * 16) ^ ((row & 7) << 4));
            bq[n] = *(const half8*)(sb + byte);
        }
        __builtin_amdgcn_s_setprio(1);
#pragma unroll
        for (int m = 0; m < 4; ++m)
#pragma unroll
            for (int n = 0; n < 4; ++n)
                acc[m][n] = __builtin_amdgcn_mfma_f32_16x16x32_f16(af[m], bq[n], acc[m][n], 0, 0, 0);
        __builtin_amdgcn_s_setprio(0);
    }

    __syncthreads();  // all waves done with staging LDS before xch overwrites it

    // ---- all 8 waves write partials to the exchange ----
    // element (row64 = m*16 + lhi*4 + r, col = n*16 + l15) of region (rsub,cidx)
    {
        const int cidx = kh * 2 + wp;
        const int rbase = (rsub * 4 + cidx) * 4224;
#pragma unroll
        for (int m = 0; m < 4; ++m)
#pragma unroll
            for (int n = 0; n < 4; ++n)
#pragma unroll
                for (int r = 0; r < 4; ++r)
                    xch[rbase + (m * 4 + n) * 264 + r * 64 + lane] = acc[m][n][r];
    }
    __syncthreads();

    // ---- all 512 threads: one row x 16 contiguous cols each ----
    {
        const int row  = tid >> 2;           // 0..127
        const int rsb  = row >> 6;
        const int r64  = row & 63;
        const int m    = r64 >> 4;
        const int lh   = (r64 & 15) >> 2;
        const int rr   = r64 & 3;
        const int n    = tid & 3;
        const int ebase = (m * 4 + n) * 264 + rr * 64 + lh * 16;

        f32x4 sum[4] = {};
#pragma unroll
        for (int c = 0; c < 4; ++c) {
            const float* p = xch + (rsb * 4 + c) * 4224 + ebase;
#pragma unroll
            for (int q = 0; q < 4; ++q)
                sum[q] += *(const f32x4*)(p + 4 * q);
        }

        const int grow = bm * 128 + row;
        const int gcol = bn * 64 + n * 16;
        const size_t gidx = (size_t)grow * DIM + gcol;

        unsigned short hh[16];
#pragma unroll
        for (int q = 0; q < 4; ++q) {
            f32x4 v = sum[q] + *(const f32x4*)&bias[gcol + 4 * q];
            if (MODE == 0) {
#pragma unroll
                for (int j = 0; j < 4; ++j) hh[q * 4 + j] = f2h(tanhf(v[j]));
            } else if (MODE == 1) {
                *(f32x4*)&accb[gidx + 4 * q] = v;
                f32x4 z = *(const f32x4*)&zbuf[gidx + 4 * q];
#pragma unroll
                for (int j = 0; j < 4; ++j) hh[q * 4 + j] = f2h(z[j] + (0.5f * hstep) * v[j]);
            } else if (MODE == 2 || MODE == 3) {
                f32x4 a0 = *(const f32x4*)&accb[gidx + 4 * q];
                a0 += 2.0f * v;
                *(f32x4*)&accb[gidx + 4 * q] = a0;
                f32x4 z = *(const f32x4*)&zbuf[gidx + 4 * q];
                const float cc = (MODE == 2) ? 0.5f * hstep : hstep;
#pragma unroll
                for (int j = 0; j < 4; ++j) hh[q * 4 + j] = f2h(z[j] + cc * v[j]);
            } else {  // MODE 4
                f32x4 a0 = *(const f32x4*)&accb[gidx + 4 * q];
                f32x4 z  = *(const f32x4*)&zbuf[gidx + 4 * q];
                f32x4 zn;
#pragma unroll
                for (int j = 0; j < 4; ++j) zn[j] = z[j] + (hstep / 6.0f) * (a0[j] + v[j]);
                *(f32x4*)&zbuf[gidx + 4 * q] = zn;
#pragma unroll
                for (int j = 0; j < 4; ++j) hh[q * 4 + j] = f2h(zn[j]);
            }
        }
        short8 s0, s1;
#pragma unroll
        for (int j = 0; j < 8; ++j) { s0[j] = (short)hh[j]; s1[j] = (short)hh[j + 8]; }
        if (MODE == 0) {
            *(short8*)&hidOut[gidx] = s0;  *(short8*)&hidOut[gidx + 8] = s1;
        } else {
            *(short8*)&zinOut[gidx] = s0;  *(short8*)&zinOut[gidx + 8] = s1;
        }
    }
}

// ---------------------------------------------------------------------------
extern "C" void kernel_launch(void* const* d_in, const int* in_sizes, int n_in,
                              void* d_out, int out_size, void* d_ws, size_t ws_size,
                              hipStream_t stream) {
    (void)in_sizes; (void)n_in; (void)out_size; (void)ws_size;
    const float* z0 = (const float*)d_in[0];
    const float* W1 = (const float*)d_in[1];
    const float* b1 = (const float*)d_in[2];
    const float* W2 = (const float*)d_in[3];
    const float* b2 = (const float*)d_in[4];
    float* zbuf = (float*)d_out;  // fp32 state lives in d_out

    char* ws = (char*)d_ws;
    unsigned short* W1T = (unsigned short*)(ws);                 // 2 MB  f16 [H][D]
    unsigned short* W2T = (unsigned short*)(ws + (2u  << 20));   // 2 MB  f16 [D][H]
    unsigned short* zin = (unsigned short*)(ws + (4u  << 20));   // 4 MB  f16
    unsigned short* hid = (unsigned short*)(ws + (8u  << 20));   // 4 MB  f16
    float*         accb = (float*)         (ws + (12u << 20));   // 8 MB  fp32

    prep_all<<<(BATCH * DIM / 4) / 256, 256, 0, stream>>>(W1, W2, z0, zbuf, W1T, W2T, zin);

    dim3 ggrid(DIM / 64, BATCH / 128);  // 16 x 16 = 256 blocks
    for (int s = 0; s < NSTEPS; ++s) {
        gemm8w<0><<<ggrid, 512, 0, stream>>>(zin, W1T, b1, hid, nullptr, nullptr, nullptr);
        gemm8w<1><<<ggrid, 512, 0, stream>>>(hid, W2T, b2, nullptr, zbuf, accb, zin);
        gemm8w<0><<<ggrid, 512, 0, stream>>>(zin, W1T, b1, hid, nullptr, nullptr, nullptr);
        gemm8w<2><<<ggrid, 512, 0, stream>>>(hid, W2T, b2, nullptr, zbuf, accb, zin);
        gemm8w<0><<<ggrid, 512, 0, stream>>>(zin, W1T, b1, hid, nullptr, nullptr, nullptr);
        gemm8w<3><<<ggrid, 512, 0, stream>>>(hid, W2T, b2, nullptr, zbuf, accb, zin);
        gemm8w<0><<<ggrid, 512, 0, stream>>>(zin, W1T, b1, hid, nullptr, nullptr, nullptr);
        gemm8w<4><<<ggrid, 512, 0, stream>>>(hid, W2T, b2, nullptr, zbuf, accb, zin);
    }
}

// Round 8
// 163.055 us; speedup vs baseline: 9.5683x; 1.3121x over previous
//
#include <hip/hip_runtime.h>
#include <hip/hip_bf16.h>
#include <cstdint>
#include <cstddef>

#define BATCH   2048
#define DIM     1024   // D == H == 1024
#define NSTEPS  2      // RK3 steps; h = 1/NSTEPS

typedef __attribute__((ext_vector_type(8))) short short8;
typedef __attribute__((ext_vector_type(4))) float f32x4;
typedef _Float16 half8 __attribute__((ext_vector_type(8)));

static __device__ __forceinline__ unsigned short f2h(float x) {
    _Float16 h = (_Float16)x;                    // v_cvt_f16_f32 (RTN)
    return __builtin_bit_cast(unsigned short, h);
}

// ---------------------------------------------------------------------------
// Fused prep (ONE dispatch): z/zin init (all 2048 blocks) + W1/W2 transpose
// to f16 [N][K] (blocks 0..511, one 64x64 tile each).
// ---------------------------------------------------------------------------
__global__ __launch_bounds__(256) void prep_all(const float* __restrict__ W1,
                                                const float* __restrict__ W2,
                                                const float* __restrict__ z0,
                                                float* __restrict__ z,
                                                unsigned short* __restrict__ W1T,
                                                unsigned short* __restrict__ W2T,
                                                unsigned short* __restrict__ zin) {
    __shared__ unsigned short tile[64][65];
    const int b = blockIdx.x;

    {   // init: one float4 per thread
        const int i = b * 256 + threadIdx.x;
        float4 v = ((const float4*)z0)[i];
        ((float4*)z)[i] = v;
        ushort4 q;
        q.x = f2h(v.x); q.y = f2h(v.y); q.z = f2h(v.z); q.w = f2h(v.w);
        ((ushort4*)zin)[i] = q;
    }

    if (b < 512) {  // transpose one 64x64 tile of W1 (b<256) or W2
        const float* in = (b < 256) ? W1 : W2;
        unsigned short* out = (b < 256) ? W1T : W2T;
        const int tb = b & 255;
        const int nb = (tb & 15) * 64, kb = (tb >> 4) * 64;
        const int cx = threadIdx.x & 63, ry = threadIdx.x >> 6;
#pragma unroll
        for (int r = 0; r < 16; ++r) {
            int k = r * 4 + ry;
            tile[cx][k] = f2h(in[(size_t)(kb + k) * DIM + (nb + cx)]);
        }
        __syncthreads();
#pragma unroll
        for (int r = 0; r < 16; ++r) {
            int n = r * 4 + ry;
            out[(size_t)(nb + n) * DIM + (kb + cx)] = tile[n][cx];
        }
    }
}

// ---------------------------------------------------------------------------
// GEMM: C[m][n] = sum_k A[m][k] * Bw[n][k]  (+ fused epilogue), f16 inputs.
//
// Main loop: block tile 128x64, 8 waves (2/SIMD). Wave = (wp = kk parity,
// rsub = row half, kh = K half); partial 64x64 per wave (4x4 frags of
// mfma_f32_16x16x32_f16). Triple-buffered LDS + counted-vmcnt pipeline (T3/T4).
// XCD-aware block swizzle (T1): 1-D grid 256, each XCD owns a 4(bm)x8(bn)
// region -> per-XCD L2 tile working set ~2 MB instead of ~4.25 MB.
//
// Epilogue: all 8 waves write partials to a 135 KB LDS exchange, then all
// 512 threads own one row x 16 contiguous cols (vectorized global I/O).
//
// Kutta RK3 (h = 1/NSTEPS):
//   MODE 0: hid = f16(tanh(C+b))
//   MODE 1 (k1): accb = k;            zin = f16(z + (h/2) k)
//   MODE 2 (k2): a0 = accb (=k1);     zin = f16(z + h (2k - a0)); accb = a0 + 4k
//   MODE 3 (k3): z += (h/6)(accb + k); zin = f16(z)
// ---------------------------------------------------------------------------
template<int MODE>
__global__ __launch_bounds__(512) void gemm8w(const unsigned short* __restrict__ A,
                                              const unsigned short* __restrict__ Bw,
                                              const float* __restrict__ bias,
                                              unsigned short* __restrict__ hidOut,
                                              float* __restrict__ zbuf,
                                              float* __restrict__ accb,
                                              unsigned short* __restrict__ zinOut) {
    constexpr float hstep = 1.0f / NSTEPS;
    __shared__ char smem_raw[147456];            // 144 KB (staging ∪ exchange)
    short8* stg = (short8*)smem_raw;             // 3 bufs x 3072 slots
    float*  xch = (float*)smem_raw;              // 8 regions x 4224 f32 = 135 KB

    const int tid  = threadIdx.x;
    const int wave = tid >> 6;
    const int lane = tid & 63;
    const int l15 = lane & 15, lhi = lane >> 4;
    const int wp   = wave & 1;         // kk parity
    const int rsub = (wave >> 1) & 1;  // row half
    const int kh   = wave >> 2;        // K half

    // XCD swizzle: bid%8 = XCD (heuristic); XCD (ry,rx) owns bm in [ry*4,+4),
    // bn in [rx*8,+8). Bijective for grid 256.
    const int bid = blockIdx.x;
    const int xcd = bid & 7, loc = bid >> 3;
    const int bm = (xcd >> 1) * 4 + (loc >> 3);
    const int bn = (xcd & 1) * 8 + (loc & 7);

    f32x4 acc[4][4] = {};

    // Staging: 6 global_load_lds per thread (4 A + 2 B) cover 3072 slots.
    // LDS slot s (linear dest) holds global (row = s>>3, k16 = (s&7)^(row&7)).
    int offA[4], offB[2];
#pragma unroll
    for (int c = 0; c < 4; ++c) {
        const int g = c * 512 + tid;           // [0,2048)
        const int half = g >> 10, s = g & 1023;
        const int row = s >> 3, k16 = (s & 7) ^ (row & 7);
        offA[c] = (bm * 128 + row) * DIM + half * 512 + k16 * 8;
    }
#pragma unroll
    for (int c = 0; c < 2; ++c) {
        const int g = c * 512 + tid;           // [0,1024)
        const int half = g >> 9, s = g & 511;
        const int row = s >> 3, k16 = (s & 7) ^ (row & 7);
        offB[c] = (bn * 64 + row) * DIM + half * 512 + k16 * 8;
    }

    auto stage = [&](int sbuf, int t) {
#pragma unroll
        for (int c = 0; c < 4; ++c)
            __builtin_amdgcn_global_load_lds(
                (const __attribute__((address_space(1))) void*)(A + offA[c] + t * 64),
                (__attribute__((address_space(3))) void*)&stg[sbuf * 3072 + c * 512 + (wave << 6)],
                16, 0, 0);
#pragma unroll
        for (int c = 0; c < 2; ++c)
            __builtin_amdgcn_global_load_lds(
                (const __attribute__((address_space(1))) void*)(Bw + offB[c] + t * 64),
                (__attribute__((address_space(3))) void*)&stg[sbuf * 3072 + 2048 + c * 512 + (wave << 6)],
                16, 0, 0);
    };

    stage(0, 0);
    stage(1, 1);  // 12 loads in flight

    for (int t = 0; t < 8; ++t) {
        if (t < 7) asm volatile("s_waitcnt vmcnt(6)" ::: "memory");
        else       asm volatile("s_waitcnt vmcnt(0)" ::: "memory");
        __builtin_amdgcn_s_barrier();          // raw: no vmcnt(0) drain
        __builtin_amdgcn_sched_barrier(0);     // don't hoist stage above barrier

        if (t + 2 < 8) stage((t + 2) % 3, t + 2);

        const char* sa = (const char*)&stg[(t % 3) * 3072 + kh * 1024];
        const char* sb = (const char*)&stg[(t % 3) * 3072 + 2048 + kh * 512];
        half8 af[4], bq[4];
#pragma unroll
        for (int m = 0; m < 4; ++m) {
            const int row  = rsub * 64 + m * 16 + l15;
            const int byte = row * 128 + ((wp * 64 + lhi * 16) ^ ((row & 7) << 4));
            af[m] = *(const half8*)(sa + byte);
        }
#pragma unroll
        for (int n = 0; n < 4; ++n) {
            const int row  = n * 16 + l15;
            const int byte = row * 128 + ((wp * 64 + lhi * 16) ^ ((row & 7) << 4));
            bq[n] = *(const half8*)(sb + byte);
        }
        __builtin_amdgcn_s_setprio(1);
#pragma unroll
        for (int m = 0; m < 4; ++m)
#pragma unroll
            for (int n = 0; n < 4; ++n)
                acc[m][n] = __builtin_amdgcn_mfma_f32_16x16x32_f16(af[m], bq[n], acc[m][n], 0, 0, 0);
        __builtin_amdgcn_s_setprio(0);
    }

    __syncthreads();  // all waves done with staging LDS before xch overwrites it

    // ---- all 8 waves write partials to the exchange ----
    {
        const int cidx = kh * 2 + wp;
        const int rbase = (rsub * 4 + cidx) * 4224;
#pragma unroll
        for (int m = 0; m < 4; ++m)
#pragma unroll
            for (int n = 0; n < 4; ++n)
#pragma unroll
                for (int r = 0; r < 4; ++r)
                    xch[rbase + (m * 4 + n) * 264 + r * 64 + lane] = acc[m][n][r];
    }
    __syncthreads();

    // ---- all 512 threads: one row x 16 contiguous cols each ----
    {
        const int row  = tid >> 2;           // 0..127
        const int rsb  = row >> 6;
        const int r64  = row & 63;
        const int m    = r64 >> 4;
        const int lh   = (r64 & 15) >> 2;
        const int rr   = r64 & 3;
        const int n    = tid & 3;
        const int ebase = (m * 4 + n) * 264 + rr * 64 + lh * 16;

        f32x4 sum[4] = {};
#pragma unroll
        for (int c = 0; c < 4; ++c) {
            const float* p = xch + (rsb * 4 + c) * 4224 + ebase;
#pragma unroll
            for (int q = 0; q < 4; ++q)
                sum[q] += *(const f32x4*)(p + 4 * q);
        }

        const int grow = bm * 128 + row;
        const int gcol = bn * 64 + n * 16;
        const size_t gidx = (size_t)grow * DIM + gcol;

        unsigned short hh[16];
#pragma unroll
        for (int q = 0; q < 4; ++q) {
            f32x4 v = sum[q] + *(const f32x4*)&bias[gcol + 4 * q];
            if (MODE == 0) {
#pragma unroll
                for (int j = 0; j < 4; ++j) hh[q * 4 + j] = f2h(tanhf(v[j]));
            } else if (MODE == 1) {        // k1
                *(f32x4*)&accb[gidx + 4 * q] = v;
                f32x4 z = *(const f32x4*)&zbuf[gidx + 4 * q];
#pragma unroll
                for (int j = 0; j < 4; ++j) hh[q * 4 + j] = f2h(z[j] + (0.5f * hstep) * v[j]);
            } else if (MODE == 2) {        // k2
                f32x4 a0 = *(const f32x4*)&accb[gidx + 4 * q];     // = k1
                f32x4 z  = *(const f32x4*)&zbuf[gidx + 4 * q];
#pragma unroll
                for (int j = 0; j < 4; ++j)
                    hh[q * 4 + j] = f2h(z[j] + hstep * (2.0f * v[j] - a0[j]));
                a0 += 4.0f * v;
                *(f32x4*)&accb[gidx + 4 * q] = a0;                 // k1 + 4 k2
            } else {                       // MODE 3: k3, finalize step
                f32x4 a0 = *(const f32x4*)&accb[gidx + 4 * q];
                f32x4 z  = *(const f32x4*)&zbuf[gidx + 4 * q];
                f32x4 zn;
#pragma unroll
                for (int j = 0; j < 4; ++j) zn[j] = z[j] + (hstep / 6.0f) * (a0[j] + v[j]);
                *(f32x4*)&zbuf[gidx + 4 * q] = zn;
#pragma unroll
                for (int j = 0; j < 4; ++j) hh[q * 4 + j] = f2h(zn[j]);
            }
        }
        short8 s0, s1;
#pragma unroll
        for (int j = 0; j < 8; ++j) { s0[j] = (short)hh[j]; s1[j] = (short)hh[j + 8]; }
        if (MODE == 0) {
            *(short8*)&hidOut[gidx] = s0;  *(short8*)&hidOut[gidx + 8] = s1;
        } else {
            *(short8*)&zinOut[gidx] = s0;  *(short8*)&zinOut[gidx + 8] = s1;
        }
    }
}

// ---------------------------------------------------------------------------
extern "C" void kernel_launch(void* const* d_in, const int* in_sizes, int n_in,
                              void* d_out, int out_size, void* d_ws, size_t ws_size,
                              hipStream_t stream) {
    (void)in_sizes; (void)n_in; (void)out_size; (void)ws_size;
    const float* z0 = (const float*)d_in[0];
    const float* W1 = (const float*)d_in[1];
    const float* b1 = (const float*)d_in[2];
    const float* W2 = (const float*)d_in[3];
    const float* b2 = (const float*)d_in[4];
    float* zbuf = (float*)d_out;  // fp32 state lives in d_out

    char* ws = (char*)d_ws;
    unsigned short* W1T = (unsigned short*)(ws);                 // 2 MB  f16 [H][D]
    unsigned short* W2T = (unsigned short*)(ws + (2u  << 20));   // 2 MB  f16 [D][H]
    unsigned short* zin = (unsigned short*)(ws + (4u  << 20));   // 4 MB  f16
    unsigned short* hid = (unsigned short*)(ws + (8u  << 20));   // 4 MB  f16
    float*         accb = (float*)         (ws + (12u << 20));   // 8 MB  fp32

    prep_all<<<(BATCH * DIM / 4) / 256, 256, 0, stream>>>(W1, W2, z0, zbuf, W1T, W2T, zin);

    for (int s = 0; s < NSTEPS; ++s) {  // Kutta RK3: 3 stages x 2 GEMMs
        gemm8w<0><<<256, 512, 0, stream>>>(zin, W1T, b1, hid, nullptr, nullptr, nullptr);
        gemm8w<1><<<256, 512, 0, stream>>>(hid, W2T, b2, nullptr, zbuf, accb, zin);
        gemm8w<0><<<256, 512, 0, stream>>>(zin, W1T, b1, hid, nullptr, nullptr, nullptr);
        gemm8w<2><<<256, 512, 0, stream>>>(hid, W2T, b2, nullptr, zbuf, accb, zin);
        gemm8w<0><<<256, 512, 0, stream>>>(zin, W1T, b1, hid, nullptr, nullptr, nullptr);
        gemm8w<3><<<256, 512, 0, stream>>>(hid, W2T, b2, nullptr, zbuf, accb, zin);
    }
}